// Round 1
// baseline (9983.676 us; speedup 1.0000x reference)
//
#include <hip/hip_runtime.h>
#include <hip/hip_bf16.h>
#include <math.h>

// Problem constants (B,S,D,H) = (4,2048,1024,16), HD=64
#define BATCH 4
#define SEQ   2048
#define DMODEL 1024
#define NHEAD 16
#define HDIM  64
#define MROWS (BATCH*SEQ)   // 8192

// ---------------------------------------------------------------------------
// GEMM: C[M,N] = A[M,K] @ W[N,K]^T + bias[N]   (fp32, 128x128x16 tiles)
// ---------------------------------------------------------------------------
#define BM 128
#define BN 128
#define BK 16

__global__ __launch_bounds__(256) void gemm_abT_bias(
    const float* __restrict__ A, const float* __restrict__ W,
    const float* __restrict__ bias, float* __restrict__ C,
    int M, int N, int K)
{
    __shared__ float As[BK][BM + 4];   // 132 stride: 16B-aligned rows, low conflict
    __shared__ float Ws[BK][BN + 4];

    const int t  = threadIdx.x;
    const int tx = t & 15;    // n direction (8 cols each)
    const int ty = t >> 4;    // m direction (8 rows each)
    const int bm = blockIdx.y * BM;
    const int bn = blockIdx.x * BN;

    float acc[8][8] = {};

    for (int k0 = 0; k0 < K; k0 += BK) {
        // Stage 128x16 tiles of A and W (2048 elems each, 8 per thread)
        #pragma unroll
        for (int i = 0; i < 8; i++) {
            int idx = (i << 8) + t;       // 0..2047
            int kk  = idx & 15;
            int r   = idx >> 4;           // 0..127
            As[kk][r] = A[(size_t)(bm + r) * K + (k0 + kk)];
            Ws[kk][r] = W[(size_t)(bn + r) * K + (k0 + kk)];
        }
        __syncthreads();

        #pragma unroll
        for (int kk = 0; kk < BK; kk++) {
            float a[8], b[8];
            #pragma unroll
            for (int i = 0; i < 8; i++) a[i] = As[kk][(ty << 3) + i];
            #pragma unroll
            for (int j = 0; j < 8; j++) b[j] = Ws[kk][(tx << 3) + j];
            #pragma unroll
            for (int i = 0; i < 8; i++)
                #pragma unroll
                for (int j = 0; j < 8; j++)
                    acc[i][j] = fmaf(a[i], b[j], acc[i][j]);
        }
        __syncthreads();
    }

    #pragma unroll
    for (int i = 0; i < 8; i++) {
        int m = bm + (ty << 3) + i;
        #pragma unroll
        for (int j = 0; j < 8; j++) {
            int n = bn + (tx << 3) + j;
            C[(size_t)m * N + n] = acc[i][j] + bias[n];
        }
    }
}

// ---------------------------------------------------------------------------
// RoPE applied in-place to Q and K, layout [B*S, D] with col = h*64 + d
// pair (i, i+32) within each head, pos = s
// ---------------------------------------------------------------------------
__global__ __launch_bounds__(256) void rope_qk(float* __restrict__ Q, float* __restrict__ K)
{
    int idx = blockIdx.x * blockDim.x + threadIdx.x;  // 0 .. B*S*H*32-1 (2^22)
    int i = idx & 31;
    int h = (idx >> 5) & 15;
    int s = (idx >> 9) & 2047;
    int b = idx >> 20;

    float inv  = __powf(10000.0f, -(float)i / 32.0f);
    float f    = (float)s * inv;
    float c = cosf(f);
    float sn = sinf(f);

    size_t off = ((size_t)(b * SEQ + s)) * DMODEL + h * HDIM + i;

    float q1 = Q[off], q2 = Q[off + 32];
    Q[off]      = q1 * c - q2 * sn;
    Q[off + 32] = q2 * c + q1 * sn;

    float k1 = K[off], k2 = K[off + 32];
    K[off]      = k1 * c - k2 * sn;
    K[off + 32] = k2 * c + k1 * sn;
}

// ---------------------------------------------------------------------------
// Causal attention, online softmax. One wave per (b,h,q) row; lane = head dim.
// Q,K,V,O layout: [B*S, D] with col = h*64 + d  (i.e. merged layout)
// ---------------------------------------------------------------------------
__global__ __launch_bounds__(256) void attn_fwd(
    const float* __restrict__ Q, const float* __restrict__ K,
    const float* __restrict__ V, float* __restrict__ O)
{
    int wave = (blockIdx.x << 2) | (threadIdx.x >> 6);  // 0 .. B*H*S-1
    int lane = threadIdx.x & 63;

    int q  = wave & (SEQ - 1);
    int hb = wave >> 11;
    int h  = hb & (NHEAD - 1);
    int b  = hb >> 4;

    size_t rowq = ((size_t)(b * SEQ + q)) * DMODEL + h * HDIM + lane;
    size_t base = ((size_t)(b * SEQ)) * DMODEL + h * HDIM + lane;

    float qv = Q[rowq] * 0.125f;   // fold 1/sqrt(HD)
    float m = -INFINITY, l = 0.0f, acc = 0.0f;

    for (int j = 0; j <= q; j++) {
        float s = qv * K[base + (size_t)j * DMODEL];
        #pragma unroll
        for (int off = 32; off; off >>= 1) s += __shfl_xor(s, off, 64);

        float nm    = fmaxf(m, s);
        float alpha = __expf(m - nm);   // first iter: exp(-inf)=0
        float p     = __expf(s - nm);
        l   = l * alpha + p;
        acc = fmaf(p, V[base + (size_t)j * DMODEL], acc * alpha);
        m   = nm;
    }
    O[rowq] = acc / l;
}

// ---------------------------------------------------------------------------
extern "C" void kernel_launch(void* const* d_in, const int* in_sizes, int n_in,
                              void* d_out, int out_size, void* d_ws, size_t ws_size,
                              hipStream_t stream)
{
    const float* x  = (const float*)d_in[0];
    const float* Wq = (const float*)d_in[1];
    const float* bq = (const float*)d_in[2];
    const float* Wk = (const float*)d_in[3];
    const float* bk = (const float*)d_in[4];
    const float* Wv = (const float*)d_in[5];
    const float* bv = (const float*)d_in[6];
    const float* Wo = (const float*)d_in[7];
    const float* bo = (const float*)d_in[8];
    // d_in[9] = attn_mask (causal, known statically — unused)

    float* out = (float*)d_out;

    size_t sz = (size_t)MROWS * DMODEL;
    float* Qb = (float*)d_ws;
    float* Kb = Qb + sz;
    float* Vb = Kb + sz;
    float* Ab = Vb + sz;

    dim3 gemm_grid(DMODEL / BN, MROWS / BM);  // (8, 64)
    dim3 gemm_block(256);

    gemm_abT_bias<<<gemm_grid, gemm_block, 0, stream>>>(x, Wq, bq, Qb, MROWS, DMODEL, DMODEL);
    gemm_abT_bias<<<gemm_grid, gemm_block, 0, stream>>>(x, Wk, bk, Kb, MROWS, DMODEL, DMODEL);
    gemm_abT_bias<<<gemm_grid, gemm_block, 0, stream>>>(x, Wv, bv, Vb, MROWS, DMODEL, DMODEL);

    int rope_threads = BATCH * SEQ * NHEAD * 32;   // 2^22
    rope_qk<<<rope_threads / 256, 256, 0, stream>>>(Qb, Kb);

    attn_fwd<<<(BATCH * NHEAD * SEQ) / 4, 256, 0, stream>>>(Qb, Kb, Vb, Ab);

    gemm_abT_bias<<<gemm_grid, gemm_block, 0, stream>>>(Ab, Wo, bo, out, MROWS, DMODEL, DMODEL);
}

// Round 2
// 1900.993 us; speedup vs baseline: 5.2518x; 5.2518x over previous
//
#include <hip/hip_runtime.h>
#include <hip/hip_bf16.h>
#include <math.h>

// Problem constants (B,S,D,H) = (4,2048,1024,16), HD=64
#define BATCH 4
#define SEQ   2048
#define DMODEL 1024
#define NHEAD 16
#define HDIM  64
#define MROWS (BATCH*SEQ)   // 8192

// ---------------------------------------------------------------------------
// GEMM: C[M,N] = A[M,K] @ W[N,K]^T + bias[N]   (fp32, 128x128x16 tiles)
// ---------------------------------------------------------------------------
#define BM 128
#define BN 128
#define BK 16

__global__ __launch_bounds__(256) void gemm_abT_bias(
    const float* __restrict__ A, const float* __restrict__ W,
    const float* __restrict__ bias, float* __restrict__ C,
    int M, int N, int K)
{
    __shared__ float As[BK][BM + 4];
    __shared__ float Ws[BK][BN + 4];

    const int t  = threadIdx.x;
    const int tx = t & 15;
    const int ty = t >> 4;
    const int bm = blockIdx.y * BM;
    const int bn = blockIdx.x * BN;

    float acc[8][8] = {};

    for (int k0 = 0; k0 < K; k0 += BK) {
        #pragma unroll
        for (int i = 0; i < 8; i++) {
            int idx = (i << 8) + t;
            int kk  = idx & 15;
            int r   = idx >> 4;
            As[kk][r] = A[(size_t)(bm + r) * K + (k0 + kk)];
            Ws[kk][r] = W[(size_t)(bn + r) * K + (k0 + kk)];
        }
        __syncthreads();

        #pragma unroll
        for (int kk = 0; kk < BK; kk++) {
            float a[8], b[8];
            #pragma unroll
            for (int i = 0; i < 8; i++) a[i] = As[kk][(ty << 3) + i];
            #pragma unroll
            for (int j = 0; j < 8; j++) b[j] = Ws[kk][(tx << 3) + j];
            #pragma unroll
            for (int i = 0; i < 8; i++)
                #pragma unroll
                for (int j = 0; j < 8; j++)
                    acc[i][j] = fmaf(a[i], b[j], acc[i][j]);
        }
        __syncthreads();
    }

    #pragma unroll
    for (int i = 0; i < 8; i++) {
        int m = bm + (ty << 3) + i;
        #pragma unroll
        for (int j = 0; j < 8; j++) {
            int n = bn + (tx << 3) + j;
            C[(size_t)m * N + n] = acc[i][j] + bias[n];
        }
    }
}

// ---------------------------------------------------------------------------
// RoPE in-place on Q and K, layout [B*S, D], col = h*64 + d, pair (i, i+32)
// ---------------------------------------------------------------------------
__global__ __launch_bounds__(256) void rope_qk(float* __restrict__ Q, float* __restrict__ K)
{
    int idx = blockIdx.x * blockDim.x + threadIdx.x;
    int i = idx & 31;
    int h = (idx >> 5) & 15;
    int s = (idx >> 9) & 2047;
    int b = idx >> 20;

    float inv  = __powf(10000.0f, -(float)i / 32.0f);
    float f    = (float)s * inv;
    float c = cosf(f);
    float sn = sinf(f);

    size_t off = ((size_t)(b * SEQ + s)) * DMODEL + h * HDIM + i;

    float q1 = Q[off], q2 = Q[off + 32];
    Q[off]      = q1 * c - q2 * sn;
    Q[off + 32] = q2 * c + q1 * sn;

    float k1 = K[off], k2 = K[off + 32];
    K[off]      = k1 * c - k2 * sn;
    K[off + 32] = k2 * c + k1 * sn;
}

// ---------------------------------------------------------------------------
// Tiled flash attention (fp32). One workgroup per (b,h,q-tile of 64).
// K/V staged in LDS 64x64; S=QK^T mini-GEMM; online softmax; PV accumulate.
// ---------------------------------------------------------------------------
#define QT 64
#define KT 64
#define LROW (HDIM + 4)   // 68 floats: keeps float4 alignment

__global__ __launch_bounds__(256) void attn_fwd_tiled(
    const float* __restrict__ Q, const float* __restrict__ K,
    const float* __restrict__ V, float* __restrict__ O)
{
    __shared__ float Qs[QT][LROW];
    __shared__ float Ks[KT][LROW];
    __shared__ float Vs[KT][LROW];
    __shared__ float Ss[QT][LROW];
    __shared__ float mS[QT], lS[QT], aS[QT];

    const int t  = threadIdx.x;
    const int qt = blockIdx.x;        // 0..31
    const int bh = blockIdx.y;        // 0..63
    const int h  = bh & (NHEAD - 1);
    const int b  = bh >> 4;
    const int q0 = qt * QT;

    const size_t rowbase = ((size_t)(b * SEQ)) * DMODEL + h * HDIM;

    // Load Q tile, folding the 1/sqrt(HD) scale
    #pragma unroll
    for (int i = 0; i < 4; i++) {
        int idx = t + (i << 8);
        int r = idx >> 4, c = (idx & 15) << 2;
        float4 v = *(const float4*)&Q[rowbase + (size_t)(q0 + r) * DMODEL + c];
        *(float4*)&Qs[r][c] = make_float4(v.x * 0.125f, v.y * 0.125f, v.z * 0.125f, v.w * 0.125f);
    }
    if (t < QT) { mS[t] = -1e30f; lS[t] = 0.0f; }

    const int tx = t & 15, ty = t >> 4;
    float acc[4][4] = {};   // O block: rows 4ty+i, cols 4tx+j

    for (int kt = 0; kt <= qt; kt++) {
        const int k0 = kt * KT;
        __syncthreads();   // protect Ks/Vs/Ss from previous iteration's readers

        #pragma unroll
        for (int i = 0; i < 4; i++) {
            int idx = t + (i << 8);
            int r = idx >> 4, c = (idx & 15) << 2;
            *(float4*)&Ks[r][c] = *(const float4*)&K[rowbase + (size_t)(k0 + r) * DMODEL + c];
            *(float4*)&Vs[r][c] = *(const float4*)&V[rowbase + (size_t)(k0 + r) * DMODEL + c];
        }
        __syncthreads();

        // ---- S = Q K^T. Thread covers rows 4ty+i, cols tx+16j (strided cols
        //      so K row reads are consecutive rows -> conflict-free)
        float s[4][4] = {};
        for (int kk = 0; kk < HDIM; kk += 4) {
            float4 a[4], bb[4];
            #pragma unroll
            for (int i = 0; i < 4; i++) a[i] = *(const float4*)&Qs[(ty << 2) + i][kk];
            #pragma unroll
            for (int j = 0; j < 4; j++) bb[j] = *(const float4*)&Ks[tx + (j << 4)][kk];
            #pragma unroll
            for (int i = 0; i < 4; i++)
                #pragma unroll
                for (int j = 0; j < 4; j++) {
                    s[i][j] = fmaf(a[i].x, bb[j].x, s[i][j]);
                    s[i][j] = fmaf(a[i].y, bb[j].y, s[i][j]);
                    s[i][j] = fmaf(a[i].z, bb[j].z, s[i][j]);
                    s[i][j] = fmaf(a[i].w, bb[j].w, s[i][j]);
                }
        }
        const bool diag = (kt == qt);
        #pragma unroll
        for (int i = 0; i < 4; i++) {
            int r = (ty << 2) + i;
            #pragma unroll
            for (int j = 0; j < 4; j++) {
                int c = tx + (j << 4);
                Ss[r][c] = (diag && c > r) ? -1e30f : s[i][j];
            }
        }
        __syncthreads();

        // ---- online softmax: row r = t>>2; 4 threads/row scan 16 cols each
        {
            int r = t >> 2, j4 = t & 3;
            float* row = &Ss[r][j4 << 4];
            float mx = -1e30f;
            #pragma unroll
            for (int c = 0; c < 16; c++) mx = fmaxf(mx, row[c]);
            mx = fmaxf(mx, __shfl_xor(mx, 1, 64));
            mx = fmaxf(mx, __shfl_xor(mx, 2, 64));
            float mold = mS[r];
            float mnew = fmaxf(mold, mx);
            float sum = 0.0f;
            #pragma unroll
            for (int c = 0; c < 16; c++) {
                float p = __expf(row[c] - mnew);
                row[c] = p;
                sum += p;
            }
            sum += __shfl_xor(sum, 1, 64);
            sum += __shfl_xor(sum, 2, 64);
            if (j4 == 0) {
                aS[r] = __expf(mold - mnew);
                mS[r] = mnew;
                lS[r] = lS[r] * aS[r] + sum;
            }
        }
        __syncthreads();

        // ---- O = O*alpha + P @ V  (cols contiguous: 4tx+j)
        #pragma unroll
        for (int i = 0; i < 4; i++) {
            float al = aS[(ty << 2) + i];
            #pragma unroll
            for (int j = 0; j < 4; j++) acc[i][j] *= al;
        }
        for (int kk = 0; kk < KT; kk += 4) {
            float4 p[4], vv[4];
            #pragma unroll
            for (int i = 0; i < 4; i++) p[i] = *(const float4*)&Ss[(ty << 2) + i][kk];
            #pragma unroll
            for (int jj = 0; jj < 4; jj++) vv[jj] = *(const float4*)&Vs[kk + jj][tx << 2];
            #pragma unroll
            for (int i = 0; i < 4; i++) {
                const float* pi = (const float*)&p[i];
                #pragma unroll
                for (int jj = 0; jj < 4; jj++) {
                    const float* vj = (const float*)&vv[jj];
                    #pragma unroll
                    for (int j = 0; j < 4; j++)
                        acc[i][j] = fmaf(pi[jj], vj[j], acc[i][j]);
                }
            }
        }
    }

    // ---- writeout: O_row / l
    #pragma unroll
    for (int i = 0; i < 4; i++) {
        int r = (ty << 2) + i;
        float inv = 1.0f / lS[r];
        float4 o = make_float4(acc[i][0] * inv, acc[i][1] * inv,
                               acc[i][2] * inv, acc[i][3] * inv);
        *(float4*)&O[rowbase + (size_t)(q0 + r) * DMODEL + (tx << 2)] = o;
    }
}

// ---------------------------------------------------------------------------
extern "C" void kernel_launch(void* const* d_in, const int* in_sizes, int n_in,
                              void* d_out, int out_size, void* d_ws, size_t ws_size,
                              hipStream_t stream)
{
    const float* x  = (const float*)d_in[0];
    const float* Wq = (const float*)d_in[1];
    const float* bq = (const float*)d_in[2];
    const float* Wk = (const float*)d_in[3];
    const float* bk = (const float*)d_in[4];
    const float* Wv = (const float*)d_in[5];
    const float* bv = (const float*)d_in[6];
    const float* Wo = (const float*)d_in[7];
    const float* bo = (const float*)d_in[8];

    float* out = (float*)d_out;

    size_t sz = (size_t)MROWS * DMODEL;
    float* Qb = (float*)d_ws;
    float* Kb = Qb + sz;
    float* Vb = Kb + sz;
    float* Ab = Vb + sz;

    dim3 gemm_grid(DMODEL / BN, MROWS / BM);
    dim3 gemm_block(256);

    gemm_abT_bias<<<gemm_grid, gemm_block, 0, stream>>>(x, Wq, bq, Qb, MROWS, DMODEL, DMODEL);
    gemm_abT_bias<<<gemm_grid, gemm_block, 0, stream>>>(x, Wk, bk, Kb, MROWS, DMODEL, DMODEL);
    gemm_abT_bias<<<gemm_grid, gemm_block, 0, stream>>>(x, Wv, bv, Vb, MROWS, DMODEL, DMODEL);

    int rope_threads = BATCH * SEQ * NHEAD * 32;
    rope_qk<<<rope_threads / 256, 256, 0, stream>>>(Qb, Kb);

    attn_fwd_tiled<<<dim3(SEQ / QT, BATCH * NHEAD), 256, 0, stream>>>(Qb, Kb, Vb, Ab);

    gemm_abT_bias<<<gemm_grid, gemm_block, 0, stream>>>(Ab, Wo, bo, out, MROWS, DMODEL, DMODEL);
}

// Round 3
// 357.865 us; speedup vs baseline: 27.8979x; 5.3120x over previous
//
#include <hip/hip_runtime.h>
#include <math.h>

// Problem constants (B,S,D,H) = (4,2048,1024,16), HD=64
#define BATCH 4
#define SEQ   2048
#define DMODEL 1024
#define NHEAD 16
#define HDIM  64
#define MROWS (BATCH*SEQ)   // 8192

typedef unsigned short u16;
typedef unsigned int   u32;

using bf16x8 = __attribute__((ext_vector_type(8))) short;
using f32x4  = __attribute__((ext_vector_type(4))) float;

__device__ __forceinline__ u16 f2bf(float f) {
    u32 u = __float_as_uint(f);
    u += 0x7fffu + ((u >> 16) & 1u);
    return (u16)(u >> 16);
}
__device__ __forceinline__ u32 pack2bf(float a, float b) {
    u32 ua = __float_as_uint(a); ua += 0x7fffu + ((ua >> 16) & 1u);
    u32 ub = __float_as_uint(b); ub += 0x7fffu + ((ub >> 16) & 1u);
    return (ua >> 16) | (ub & 0xffff0000u);
}

// ---------------------------------------------------------------------------
// Convert x (8.4M) + Wq/Wk/Wv/Wo (1M each) fp32 -> bf16 into contiguous dst.
// ---------------------------------------------------------------------------
__global__ __launch_bounds__(256) void convert_inputs(
    const float* __restrict__ x,  const float* __restrict__ wq,
    const float* __restrict__ wk, const float* __restrict__ wv,
    const float* __restrict__ wo, u16* __restrict__ dst)
{
    long long i4 = ((long long)blockIdx.x * 256 + threadIdx.x) * 4;
    const float* src; long long off;
    if (i4 < 8388608LL) { src = x; off = i4; }
    else {
        long long j = i4 - 8388608LL;
        int seg = (int)(j >> 20);
        off = j & 1048575LL;
        src = (seg == 0) ? wq : (seg == 1) ? wk : (seg == 2) ? wv : wo;
    }
    float4 v = *(const float4*)(src + off);
    u32 lo = (u32)f2bf(v.x) | ((u32)f2bf(v.y) << 16);
    u32 hi = (u32)f2bf(v.z) | ((u32)f2bf(v.w) << 16);
    *(uint2*)(dst + i4) = make_uint2(lo, hi);
}

// ---------------------------------------------------------------------------
// bf16 MFMA GEMM: C[M,N] = A[M,K] @ W[N,K]^T + bias.
// 128x128 tile, BK=32, 4 waves (each 64x64 via 4x4 MFMAs of 16x16x32).
// MODE: 0 = fp32 out; 1 = bf16 out; 2 = bf16 + RoPE; 3 = bf16 + RoPE + 0.125
// LDS rows padded to 40 shorts (80 B): fragment reads are 2-way conflicts.
// ---------------------------------------------------------------------------
template<int MODE>
__global__ __launch_bounds__(256) void gemm_mfma(
    const u16* __restrict__ A, const u16* __restrict__ W,
    const float* __restrict__ bias, void* __restrict__ Cout)
{
    __shared__ u16 As[128 * 40];
    __shared__ u16 Ws[128 * 40];

    const int t    = threadIdx.x;
    const int lane = t & 63;
    const int w    = t >> 6;
    const int quad = lane >> 4;
    const int l15  = lane & 15;
    const int bn   = (blockIdx.x & 7) * 128;
    const int bm   = (blockIdx.x >> 3) * 128;
    const int wrow = (w & 1) * 64;
    const int wcol = (w >> 1) * 64;
    const int r0   = t >> 2;       // staging row within 64-row group
    const int c4   = t & 3;        // 16B chunk within 64B row

    f32x4 acc[4][4] = {};

    for (int k0 = 0; k0 < DMODEL; k0 += 32) {
        __syncthreads();
        #pragma unroll
        for (int rd = 0; rd < 2; rd++) {
            int row = rd * 64 + r0;
            uint4 va = *(const uint4*)(A + (size_t)(bm + row) * DMODEL + k0 + c4 * 8);
            uint4 vw = *(const uint4*)(W + (size_t)(bn + row) * DMODEL + k0 + c4 * 8);
            *(uint4*)&As[row * 40 + c4 * 8] = va;
            *(uint4*)&Ws[row * 40 + c4 * 8] = vw;
        }
        __syncthreads();

        bf16x8 af[4], bfr[4];
        #pragma unroll
        for (int i = 0; i < 4; i++) af[i]  = *(const bf16x8*)&As[(wrow + 16*i + l15) * 40 + quad * 8];
        #pragma unroll
        for (int j = 0; j < 4; j++) bfr[j] = *(const bf16x8*)&Ws[(wcol + 16*j + l15) * 40 + quad * 8];
        #pragma unroll
        for (int i = 0; i < 4; i++)
            #pragma unroll
            for (int j = 0; j < 4; j++)
                acc[i][j] = __builtin_amdgcn_mfma_f32_16x16x32_bf16(af[i], bfr[j], acc[i][j], 0, 0, 0);
    }

    // ---- epilogue
    float bv[4];
    #pragma unroll
    for (int j = 0; j < 4; j++) bv[j] = bias[bn + wcol + 16*j + l15];

    if constexpr (MODE == 0) {
        float* C = (float*)Cout;
        #pragma unroll
        for (int i = 0; i < 4; i++)
            #pragma unroll
            for (int r = 0; r < 4; r++) {
                int mg = bm + wrow + 16*i + quad*4 + r;
                #pragma unroll
                for (int j = 0; j < 4; j++)
                    C[(size_t)mg * DMODEL + bn + wcol + 16*j + l15] = acc[i][j][r] + bv[j];
            }
    } else if constexpr (MODE == 1) {
        u16* C = (u16*)Cout;
        #pragma unroll
        for (int i = 0; i < 4; i++)
            #pragma unroll
            for (int r = 0; r < 4; r++) {
                int mg = bm + wrow + 16*i + quad*4 + r;
                #pragma unroll
                for (int j = 0; j < 4; j++)
                    C[(size_t)mg * DMODEL + bn + wcol + 16*j + l15] = f2bf(acc[i][j][r] + bv[j]);
            }
    } else {
        // RoPE: wave's 64-col span = one head. pair (d, d+32) = j-tiles (j, j+2)
        const float qscale = (MODE == 3) ? 0.125f : 1.0f;
        u16* C = (u16*)Cout;
        float inv[2];
        #pragma unroll
        for (int j = 0; j < 2; j++) {
            int d = 16*j + l15;                          // 0..31
            inv[j] = exp2f(-(float)d * 0.4152410118609203f);  // 10000^(-d/32)
        }
        #pragma unroll
        for (int i = 0; i < 4; i++)
            #pragma unroll
            for (int r = 0; r < 4; r++) {
                int mg = bm + wrow + 16*i + quad*4 + r;
                int s  = mg & (SEQ - 1);
                #pragma unroll
                for (int j = 0; j < 2; j++) {
                    float f = (float)s * inv[j];
                    float sn, cs;
                    sincosf(f, &sn, &cs);
                    float a1 = acc[i][j][r]     + bv[j];
                    float a2 = acc[i][j + 2][r] + bv[j + 2];
                    float o1 = (a1 * cs - a2 * sn) * qscale;
                    float o2 = (a2 * cs + a1 * sn) * qscale;
                    C[(size_t)mg * DMODEL + bn + wcol + 16*j       + l15] = f2bf(o1);
                    C[(size_t)mg * DMODEL + bn + wcol + 16*(j + 2) + l15] = f2bf(o2);
                }
            }
    }
}

// ---------------------------------------------------------------------------
// MFMA flash attention (bf16 in, bf16 out), causal.
// Block = 4 waves, 64 q-rows (wave w owns rows w*16..w*16+15).
// S^T = K*Q^T (both operands k-contiguous), softmax in C-layout regs,
// P via LDS (A-layout), V staged transposed (B-operand), O accum in regs.
// All LDS tiles stride 72 shorts (144 B): frag reads are 2-way conflicts.
// ---------------------------------------------------------------------------
__global__ __launch_bounds__(256) void attn_mfma(
    const u16* __restrict__ Q, const u16* __restrict__ K,
    const u16* __restrict__ V, u16* __restrict__ O)
{
    __shared__ u16 Qs[64 * 72];
    __shared__ u16 Ks[64 * 72];
    __shared__ u16 Vt[64 * 72];
    __shared__ u16 Ps[64 * 72];
    __shared__ float aS[64];
    __shared__ float lS[64];

    const int t    = threadIdx.x;
    const int lane = t & 63;
    const int w    = t >> 6;
    const int quad = lane >> 4;
    const int l15  = lane & 15;
    const int bid  = blockIdx.x;
    const int bh   = bid & 63;
    const int qt   = 31 - (bid >> 6);    // heavy q-tiles dispatched first
    const int h    = bh & (NHEAD - 1);
    const int b    = bh >> 4;
    const int q0   = qt * 64;

    const size_t gbase = ((size_t)b * SEQ) * DMODEL + h * HDIM;  // element offset

    // ---- stage Q tile once (rows q0..q0+63)
    {
        int r0 = t >> 3, c8 = t & 7;
        #pragma unroll
        for (int rd = 0; rd < 2; rd++) {
            int row = rd * 32 + r0;
            uint4 v = *(const uint4*)(Q + gbase + (size_t)(q0 + row) * DMODEL + c8 * 8);
            *(uint4*)&Qs[row * 72 + c8 * 8] = v;
        }
    }

    float m = -1e30f, l = 0.0f;
    f32x4 oacc[4] = {};

    for (int kt = 0; kt <= qt; kt++) {
        const int k0 = kt * 64;
        const bool diag = (kt == qt);
        __syncthreads();   // protect Ks/Vt (and first-iter Qs) ordering

        // ---- stage K (rows k0..k0+63), padded stride
        {
            int r0 = t >> 3, c8 = t & 7;
            #pragma unroll
            for (int rd = 0; rd < 2; rd++) {
                int row = rd * 32 + r0;
                uint4 v = *(const uint4*)(K + gbase + (size_t)(k0 + row) * DMODEL + c8 * 8);
                *(uint4*)&Ks[row * 72 + c8 * 8] = v;
            }
        }
        // ---- stage V transposed: Vt[d][j] = V[k0+j][d]
        {
            int j0 = (t & 31) * 2, d0 = ((t >> 5) & 7) * 8;
            uint4 va = *(const uint4*)(V + gbase + (size_t)(k0 + j0)     * DMODEL + d0);
            uint4 vb = *(const uint4*)(V + gbase + (size_t)(k0 + j0 + 1) * DMODEL + d0);
            const u16* pa = (const u16*)&va;
            const u16* pb = (const u16*)&vb;
            #pragma unroll
            for (int e = 0; e < 8; e++) {
                u32 pk = (u32)pa[e] | ((u32)pb[e] << 16);
                *(u32*)&Vt[(d0 + e) * 72 + j0] = pk;
            }
        }
        __syncthreads();

        // ---- S^T = K * Q^T  (D[m=kr][n=q])
        bf16x8 bq0 = *(const bf16x8*)&Qs[(w * 16 + l15) * 72      + quad * 8];
        bf16x8 bq1 = *(const bf16x8*)&Qs[(w * 16 + l15) * 72 + 32 + quad * 8];

        f32x4 sT[4];
        #pragma unroll
        for (int T = 0; T < 4; T++) {
            if (diag && T > w) {   // fully-masked kr-tile for this wave
                sT[T] = (f32x4){-1e30f, -1e30f, -1e30f, -1e30f};
                continue;
            }
            bf16x8 ka0 = *(const bf16x8*)&Ks[(T * 16 + l15) * 72      + quad * 8];
            bf16x8 ka1 = *(const bf16x8*)&Ks[(T * 16 + l15) * 72 + 32 + quad * 8];
            f32x4 s4 = {};
            s4 = __builtin_amdgcn_mfma_f32_16x16x32_bf16(ka0, bq0, s4, 0, 0, 0);
            s4 = __builtin_amdgcn_mfma_f32_16x16x32_bf16(ka1, bq1, s4, 0, 0, 0);
            if (diag) {
                int qrow = w * 16 + l15;
                #pragma unroll
                for (int r = 0; r < 4; r++)
                    if (T * 16 + quad * 4 + r > qrow) s4[r] = -1e30f;
            }
            sT[T] = s4;
        }

        // ---- online softmax (per q = l15 column; replicated across quads)
        float mx = -1e30f;
        #pragma unroll
        for (int T = 0; T < 4; T++)
            #pragma unroll
            for (int r = 0; r < 4; r++) mx = fmaxf(mx, sT[T][r]);
        mx = fmaxf(mx, __shfl_xor(mx, 16, 64));
        mx = fmaxf(mx, __shfl_xor(mx, 32, 64));
        float mnew = fmaxf(m, mx);
        float al   = __expf(m - mnew);
        m = mnew;
        float rs = 0.0f;
        #pragma unroll
        for (int T = 0; T < 4; T++)
            #pragma unroll
            for (int r = 0; r < 4; r++) {
                float p = __expf(sT[T][r] - mnew);
                sT[T][r] = p;
                rs += p;
            }
        rs += __shfl_xor(rs, 16, 64);
        rs += __shfl_xor(rs, 32, 64);
        l = l * al + rs;
        if (quad == 0) aS[w * 16 + l15] = al;

        // ---- write P (bf16) to LDS in [q][kr] layout
        #pragma unroll
        for (int T = 0; T < 4; T++) {
            u32 p01 = pack2bf(sT[T][0], sT[T][1]);
            u32 p23 = pack2bf(sT[T][2], sT[T][3]);
            *(u32*)&Ps[(w * 16 + l15) * 72 + T * 16 + quad * 4]     = p01;
            *(u32*)&Ps[(w * 16 + l15) * 72 + T * 16 + quad * 4 + 2] = p23;
        }

        // ---- rescale O by alpha (row-indexed: quad*4+r)
        f32x4 alv = *(const f32x4*)&aS[w * 16 + quad * 4];
        #pragma unroll
        for (int dt = 0; dt < 4; dt++) oacc[dt] *= alv;

        // ---- O += P @ V
        bf16x8 pa0 = *(const bf16x8*)&Ps[(w * 16 + l15) * 72      + quad * 8];
        bf16x8 pa1 = *(const bf16x8*)&Ps[(w * 16 + l15) * 72 + 32 + quad * 8];
        #pragma unroll
        for (int dt = 0; dt < 4; dt++) {
            bf16x8 vb0 = *(const bf16x8*)&Vt[(dt * 16 + l15) * 72      + quad * 8];
            bf16x8 vb1 = *(const bf16x8*)&Vt[(dt * 16 + l15) * 72 + 32 + quad * 8];
            oacc[dt] = __builtin_amdgcn_mfma_f32_16x16x32_bf16(pa0, vb0, oacc[dt], 0, 0, 0);
            oacc[dt] = __builtin_amdgcn_mfma_f32_16x16x32_bf16(pa1, vb1, oacc[dt], 0, 0, 0);
        }
    }

    // ---- writeout: O / l   (bf16)
    if (quad == 0) lS[w * 16 + l15] = l;
    f32x4 lv = *(const f32x4*)&lS[w * 16 + quad * 4];
    #pragma unroll
    for (int dt = 0; dt < 4; dt++)
        #pragma unroll
        for (int r = 0; r < 4; r++) {
            float o = oacc[dt][r] / lv[r];
            int mg = q0 + w * 16 + quad * 4 + r;
            O[gbase + (size_t)mg * DMODEL + dt * 16 + l15] = f2bf(o);
        }
}

// ---------------------------------------------------------------------------
extern "C" void kernel_launch(void* const* d_in, const int* in_sizes, int n_in,
                              void* d_out, int out_size, void* d_ws, size_t ws_size,
                              hipStream_t stream)
{
    const float* x  = (const float*)d_in[0];
    const float* Wq = (const float*)d_in[1];
    const float* bq = (const float*)d_in[2];
    const float* Wk = (const float*)d_in[3];
    const float* bk = (const float*)d_in[4];
    const float* Wv = (const float*)d_in[5];
    const float* bv = (const float*)d_in[6];
    const float* Wo = (const float*)d_in[7];
    const float* bo = (const float*)d_in[8];

    u16* wsp = (u16*)d_ws;
    u16* xb  = wsp;                    // 8388608
    u16* Wqb = wsp + 8388608;          // 1048576
    u16* Wkb = Wqb + 1048576;
    u16* Wvb = Wkb + 1048576;
    u16* Wob = Wvb + 1048576;
    u16* Qb  = Wob + 1048576;          // 8388608 each
    u16* Kb  = Qb + 8388608;
    u16* Vb  = Kb + 8388608;
    u16* Ab  = Vb + 8388608;

    convert_inputs<<<12288, 256, 0, stream>>>(x, Wq, Wk, Wv, Wo, xb);

    gemm_mfma<3><<<512, 256, 0, stream>>>(xb, Wqb, bq, (void*)Qb);   // Q: rope + 0.125
    gemm_mfma<2><<<512, 256, 0, stream>>>(xb, Wkb, bk, (void*)Kb);   // K: rope
    gemm_mfma<1><<<512, 256, 0, stream>>>(xb, Wvb, bv, (void*)Vb);   // V: bf16

    attn_mfma<<<2048, 256, 0, stream>>>(Qb, Kb, Vb, Ab);

    gemm_mfma<0><<<512, 256, 0, stream>>>(Ab, Wob, bo, d_out);       // fp32 out
}

// Round 4
// 291.450 us; speedup vs baseline: 34.2552x; 1.2279x over previous
//
#include <hip/hip_runtime.h>
#include <math.h>

// Problem constants (B,S,D,H) = (4,2048,1024,16), HD=64
#define BATCH 4
#define SEQ   2048
#define DMODEL 1024
#define NHEAD 16
#define HDIM  64
#define MROWS (BATCH*SEQ)   // 8192

typedef unsigned short u16;
typedef unsigned int   u32;

using bf16x8 = __attribute__((ext_vector_type(8))) short;
using f32x4  = __attribute__((ext_vector_type(4))) float;
using f32x16 = __attribute__((ext_vector_type(16))) float;

__device__ __forceinline__ u16 f2bf(float f) {
    u32 u = __float_as_uint(f);
    u += 0x7fffu + ((u >> 16) & 1u);
    return (u16)(u >> 16);
}
__device__ __forceinline__ u32 pack2bf(float a, float b) {
    u32 ua = __float_as_uint(a); ua += 0x7fffu + ((ua >> 16) & 1u);
    u32 ub = __float_as_uint(b); ub += 0x7fffu + ((ub >> 16) & 1u);
    return (ua >> 16) | (ub & 0xffff0000u);
}

// async global->LDS, 16 B per lane; LDS dest = wave-uniform base + lane*16
#define GLOBAL_LOAD_LDS16(gp, lp)                                              \
    __builtin_amdgcn_global_load_lds(                                          \
        (const __attribute__((address_space(1))) void*)(gp),                   \
        (__attribute__((address_space(3))) void*)(lp), 16, 0, 0)

// ---------------------------------------------------------------------------
// Convert x (8.4M) + Wq/Wk/Wv/Wo (1M each) fp32 -> bf16 into contiguous dst.
// ---------------------------------------------------------------------------
__global__ __launch_bounds__(256) void convert_inputs(
    const float* __restrict__ x,  const float* __restrict__ wq,
    const float* __restrict__ wk, const float* __restrict__ wv,
    const float* __restrict__ wo, u16* __restrict__ dst)
{
    long long i4 = ((long long)blockIdx.x * 256 + threadIdx.x) * 4;
    const float* src; long long off;
    if (i4 < 8388608LL) { src = x; off = i4; }
    else {
        long long j = i4 - 8388608LL;
        int seg = (int)(j >> 20);
        off = j & 1048575LL;
        src = (seg == 0) ? wq : (seg == 1) ? wk : (seg == 2) ? wv : wo;
    }
    float4 v = *(const float4*)(src + off);
    u32 lo = (u32)f2bf(v.x) | ((u32)f2bf(v.y) << 16);
    u32 hi = (u32)f2bf(v.z) | ((u32)f2bf(v.w) << 16);
    *(uint2*)(dst + i4) = make_uint2(lo, hi);
}

// ---------------------------------------------------------------------------
// bf16 MFMA GEMM: C[M,N] = A[M,K] @ W[N,K]^T + bias.  128x128 tile, BK=32.
// Staging via global_load_lds (16B/lane), XOR-swizzled LDS (stride 32 shorts,
// physical_chunk = logical_chunk ^ (row&3)) -> conflict-free b128 frag reads.
// QKV=1: one launch covers Q/K/V (seg = blockIdx.x>>9); epilogue does
//        RoPE(+0.125 scale) for Q, RoPE for K, plain bf16 for V.
// QKV=0: fp32 output + bias (final projection).
// ---------------------------------------------------------------------------
template<int QKV>
__global__ __launch_bounds__(256) void gemm_mfma(
    const u16* __restrict__ A,
    const u16* __restrict__ Wq_, const u16* __restrict__ Wk_, const u16* __restrict__ Wv_,
    const float* __restrict__ bq_, const float* __restrict__ bk_, const float* __restrict__ bv_,
    u16* __restrict__ Cq_, u16* __restrict__ Ck_, u16* __restrict__ Cv_,
    float* __restrict__ Cf)
{
    __shared__ u16 As[128 * 32];
    __shared__ u16 Ws[128 * 32];

    const int t    = threadIdx.x;
    const int lane = t & 63;
    const int w    = t >> 6;
    const int quad = lane >> 4;
    const int l15  = lane & 15;

    int bx = blockIdx.x;
    int seg = 0;
    if (QKV) { seg = bx >> 9; bx &= 511; }
    const u16*   W    = (seg == 0) ? Wq_ : (seg == 1) ? Wk_ : Wv_;
    const float* bias = (seg == 0) ? bq_ : (seg == 1) ? bk_ : bv_;
    u16*         Cb   = (seg == 0) ? Cq_ : (seg == 1) ? Ck_ : Cv_;

    const int bn   = (bx & 7) * 128;
    const int bm   = (bx >> 3) * 128;
    const int wrow = (w & 1) * 64;
    const int wcol = (w >> 1) * 64;

    const int srl = lane >> 2;         // staging row within 16-row group
    const int scp = lane & 3;          // physical chunk this lane fills
    const int sc  = scp ^ (srl & 3);   // logical chunk -> global column

    f32x4 acc[4][4] = {};

    for (int k0 = 0; k0 < DMODEL; k0 += 32) {
        __syncthreads();
        #pragma unroll
        for (int i = 0; i < 2; i++) {
            int row = 32 * w + 16 * i + srl;
            GLOBAL_LOAD_LDS16(A + (size_t)(bm + row) * DMODEL + k0 + sc * 8,
                              &As[(32 * w + 16 * i) * 32]);
            GLOBAL_LOAD_LDS16(W + (size_t)(bn + row) * DMODEL + k0 + sc * 8,
                              &Ws[(32 * w + 16 * i) * 32]);
        }
        __syncthreads();

        bf16x8 af[4], bfr[4];
        const int pc = quad ^ (l15 & 3);
        #pragma unroll
        for (int i = 0; i < 4; i++)
            af[i] = *(const bf16x8*)&As[(wrow + 16 * i + l15) * 32 + pc * 8];
        #pragma unroll
        for (int j = 0; j < 4; j++)
            bfr[j] = *(const bf16x8*)&Ws[(wcol + 16 * j + l15) * 32 + pc * 8];
        #pragma unroll
        for (int i = 0; i < 4; i++)
            #pragma unroll
            for (int j = 0; j < 4; j++)
                acc[i][j] = __builtin_amdgcn_mfma_f32_16x16x32_bf16(af[i], bfr[j], acc[i][j], 0, 0, 0);
    }

    // ---- epilogue
    float bv[4];
    #pragma unroll
    for (int j = 0; j < 4; j++) bv[j] = bias[bn + wcol + 16 * j + l15];

    if constexpr (QKV == 0) {
        #pragma unroll
        for (int i = 0; i < 4; i++)
            #pragma unroll
            for (int r = 0; r < 4; r++) {
                int mg = bm + wrow + 16 * i + quad * 4 + r;
                #pragma unroll
                for (int j = 0; j < 4; j++)
                    Cf[(size_t)mg * DMODEL + bn + wcol + 16 * j + l15] = acc[i][j][r] + bv[j];
            }
    } else {
        if (seg == 2) {
            #pragma unroll
            for (int i = 0; i < 4; i++)
                #pragma unroll
                for (int r = 0; r < 4; r++) {
                    int mg = bm + wrow + 16 * i + quad * 4 + r;
                    #pragma unroll
                    for (int j = 0; j < 4; j++)
                        Cb[(size_t)mg * DMODEL + bn + wcol + 16 * j + l15] = f2bf(acc[i][j][r] + bv[j]);
                }
        } else {
            // RoPE: wave's 64-col span = one head; pair (d, d+32) = j-tiles (j, j+2)
            const float qscale = (seg == 0) ? 0.125f : 1.0f;
            float inv[2];
            #pragma unroll
            for (int j = 0; j < 2; j++) {
                int d = 16 * j + l15;                              // 0..31
                inv[j] = exp2f(-(float)d * 0.4152410118609203f);   // 10000^(-d/32)
            }
            #pragma unroll
            for (int i = 0; i < 4; i++)
                #pragma unroll
                for (int r = 0; r < 4; r++) {
                    int mg = bm + wrow + 16 * i + quad * 4 + r;
                    int s  = mg & (SEQ - 1);
                    #pragma unroll
                    for (int j = 0; j < 2; j++) {
                        float f = (float)s * inv[j];
                        float sn, cs;
                        __sincosf(f, &sn, &cs);
                        float a1 = acc[i][j][r]     + bv[j];
                        float a2 = acc[i][j + 2][r] + bv[j + 2];
                        float o1 = (a1 * cs - a2 * sn) * qscale;
                        float o2 = (a2 * cs + a1 * sn) * qscale;
                        Cb[(size_t)mg * DMODEL + bn + wcol + 16 * j       + l15] = f2bf(o1);
                        Cb[(size_t)mg * DMODEL + bn + wcol + 16 * (j + 2) + l15] = f2bf(o2);
                    }
                }
        }
    }
}

// ---------------------------------------------------------------------------
// MFMA flash attention v2: 32x32x16 MFMA, 128 q-rows/block, max-free softmax.
// Wave w owns q rows [32w,32w+32). S^T = K*Q^T per 64-kr tile; exp; P via LDS
// (wave-private rows, no barrier); O += P@V with V staged transposed.
// All LDS tiles: 64-short rows, XOR swizzle phys_chunk = logical ^ (row&7).
// ---------------------------------------------------------------------------
__global__ __launch_bounds__(256) void attn_mfma(
    const u16* __restrict__ Q, const u16* __restrict__ K,
    const u16* __restrict__ V, u16* __restrict__ O)
{
    __shared__ u16 Qs[128 * 64];
    __shared__ u16 Ks[64 * 64];
    __shared__ u16 Vt[64 * 64];
    __shared__ u16 Ps[128 * 64];
    __shared__ float lS[128];

    const int t    = threadIdx.x;
    const int lane = t & 63;
    const int w    = t >> 6;
    const int l31  = lane & 31;
    const int hl   = lane >> 5;         // 0/1
    const int bid  = blockIdx.x;
    const int bh   = bid & 63;
    const int qt   = 15 - (bid >> 6);   // heavy q-tiles first
    const int h    = bh & (NHEAD - 1);
    const int b    = bh >> 4;
    const int q0   = qt * 128;

    const size_t gbase = ((size_t)b * SEQ) * DMODEL + h * HDIM;

    // ---- stage Q tile (128 rows) via global_load_lds, swizzled
    {
        int rl = lane >> 3, cp = lane & 7;
        int c  = cp ^ rl;                       // logical chunk
        #pragma unroll
        for (int i = 0; i < 4; i++) {
            int row = 32 * w + 8 * i + rl;
            GLOBAL_LOAD_LDS16(Q + gbase + (size_t)(q0 + row) * DMODEL + c * 8,
                              &Qs[(32 * w + 8 * i) * 64]);
        }
    }
    __syncthreads();

    // ---- hoist Q B-fragments (loop-invariant): B[k][n=q], k = hl*8+j+16s
    bf16x8 qf[4];
    {
        int row = 32 * w + l31;
        #pragma unroll
        for (int s = 0; s < 4; s++) {
            int c = (hl + 2 * s) ^ (row & 7);
            qf[s] = *(const bf16x8*)&Qs[row * 64 + c * 8];
        }
    }

    float lsum = 0.0f;
    f32x16 oacc[2] = {};

    const int ktn = 2 * qt + 2;
    for (int kt = 0; kt < ktn; kt++) {
        const int k0 = kt * 64;
        __syncthreads();   // protect Ks/Vt from previous iteration's readers

        // ---- stage K (64 rows) via global_load_lds, swizzled
        {
            int rl = lane >> 3, cp = lane & 7;
            int c  = cp ^ rl;
            #pragma unroll
            for (int i = 0; i < 2; i++) {
                int row = 16 * w + 8 * i + rl;
                GLOBAL_LOAD_LDS16(K + gbase + (size_t)(k0 + row) * DMODEL + c * 8,
                                  &Ks[(16 * w + 8 * i) * 64]);
            }
        }
        // ---- stage V transposed: Vt[d][j] = V[k0+j][d], swizzled pair-packed
        {
            int j0 = (t & 31) * 2, d0 = (t >> 5) * 8;
            uint4 va = *(const uint4*)(V + gbase + (size_t)(k0 + j0)     * DMODEL + d0);
            uint4 vb = *(const uint4*)(V + gbase + (size_t)(k0 + j0 + 1) * DMODEL + d0);
            const u16* pa = (const u16*)&va;
            const u16* pb = (const u16*)&vb;
            int jd = t & 31, pos = jd & 3, ch = jd >> 2;
            #pragma unroll
            for (int e = 0; e < 8; e++) {
                int row = d0 + e;
                int pcch = ch ^ (row & 7);
                *(u32*)&Vt[row * 64 + pcch * 8 + pos * 2] = (u32)pa[e] | ((u32)pb[e] << 16);
            }
        }
        __syncthreads();

        const bool act = (k0 <= q0 + 32 * w + 31);
        if (act) {
            const int qrow = 32 * w + l31;           // local q row
            const int qg   = q0 + qrow;              // global q row
            #pragma unroll
            for (int krh = 0; krh < 2; krh++) {
                const bool qact = (k0 + 32 * krh <= q0 + 32 * w + 31);
                if (!qact) {
                    // fully masked quadrant: P = 0
                    #pragma unroll
                    for (int g = 0; g < 4; g++)
                        #pragma unroll
                        for (int pp = 0; pp < 2; pp++) {
                            int kr = 32 * krh + 8 * g + 4 * hl + 2 * pp;
                            int jd = kr >> 1;
                            int pcc = (jd >> 2) ^ (qrow & 7);
                            *(u32*)&Ps[qrow * 64 + pcc * 8 + (jd & 3) * 2] = 0u;
                        }
                    continue;
                }
                // ---- S^T quadrant: D[m=kr][n=q]
                f32x16 s = {};
                #pragma unroll
                for (int stp = 0; stp < 4; stp++) {
                    int row = 32 * krh + l31;
                    int c   = (hl + 2 * stp) ^ (l31 & 7);
                    bf16x8 ka = *(const bf16x8*)&Ks[row * 64 + c * 8];
                    s = __builtin_amdgcn_mfma_f32_32x32x16_bf16(ka, qf[stp], s, 0, 0, 0);
                }
                // causal mask on diagonal-crossing tiles
                if (k0 + 32 * krh + 31 > q0 + 32 * w) {
                    #pragma unroll
                    for (int r = 0; r < 16; r++) {
                        int krg = k0 + 32 * krh + (r & 3) + 8 * (r >> 2) + 4 * hl;
                        if (krg > qg) s[r] = -1e30f;
                    }
                }
                // ---- exp (max-free), accumulate l, pack P to LDS
                float pv[16];
                #pragma unroll
                for (int r = 0; r < 16; r++) { pv[r] = __expf(s[r]); lsum += pv[r]; }
                #pragma unroll
                for (int g = 0; g < 4; g++)
                    #pragma unroll
                    for (int pp = 0; pp < 2; pp++) {
                        int kr = 32 * krh + 8 * g + 4 * hl + 2 * pp;
                        int jd = kr >> 1;
                        int pcc = (jd >> 2) ^ (qrow & 7);
                        *(u32*)&Ps[qrow * 64 + pcc * 8 + (jd & 3) * 2] =
                            pack2bf(pv[4 * g + 2 * pp], pv[4 * g + 2 * pp + 1]);
                    }
            }

            // ---- O += P @ V   (A = P rows q [wave-private], B = Vt rows d)
            #pragma unroll
            for (int stp = 0; stp < 4; stp++) {
                int c = (hl + 2 * stp) ^ (l31 & 7);
                bf16x8 pf = *(const bf16x8*)&Ps[qrow * 64 + c * 8];
                #pragma unroll
                for (int dh = 0; dh < 2; dh++) {
                    bf16x8 vf = *(const bf16x8*)&Vt[(32 * dh + l31) * 64 + c * 8];
                    oacc[dh] = __builtin_amdgcn_mfma_f32_32x32x16_bf16(pf, vf, oacc[dh], 0, 0, 0);
                }
            }
        }
    }

    // ---- finalize l (cross-half reduce, through LDS to reindex q)
    lsum += __shfl_xor(lsum, 32, 64);
    if (lane < 32) lS[32 * w + lane] = lsum;
    __syncthreads();

    // ---- writeout: O / l   (C layout: col=l31=d-local, row=(r&3)+8*(r>>2)+4*hl)
    #pragma unroll
    for (int g = 0; g < 4; g++) {
        f32x4 lv = *(const f32x4*)&lS[32 * w + 8 * g + 4 * hl];
        #pragma unroll
        for (int rr = 0; rr < 4; rr++) {
            int qg = q0 + 32 * w + rr + 8 * g + 4 * hl;
            float inv = 1.0f / lv[rr];
            #pragma unroll
            for (int dh = 0; dh < 2; dh++) {
                float o = oacc[dh][4 * g + rr] * inv;
                O[gbase + (size_t)qg * DMODEL + 32 * dh + l31] = f2bf(o);
            }
        }
    }
}

// ---------------------------------------------------------------------------
extern "C" void kernel_launch(void* const* d_in, const int* in_sizes, int n_in,
                              void* d_out, int out_size, void* d_ws, size_t ws_size,
                              hipStream_t stream)
{
    const float* x  = (const float*)d_in[0];
    const float* Wq = (const float*)d_in[1];
    const float* bq = (const float*)d_in[2];
    const float* Wk = (const float*)d_in[3];
    const float* bk = (const float*)d_in[4];
    const float* Wv = (const float*)d_in[5];
    const float* bv = (const float*)d_in[6];
    const float* Wo = (const float*)d_in[7];
    const float* bo = (const float*)d_in[8];

    u16* wsp = (u16*)d_ws;
    u16* xb  = wsp;                    // 8388608
    u16* Wqb = wsp + 8388608;          // 1048576 each
    u16* Wkb = Wqb + 1048576;
    u16* Wvb = Wkb + 1048576;
    u16* Wob = Wvb + 1048576;
    u16* Qb  = Wob + 1048576;          // 8388608 each
    u16* Kb  = Qb + 8388608;
    u16* Vb  = Kb + 8388608;
    u16* Ab  = Vb + 8388608;

    convert_inputs<<<12288, 256, 0, stream>>>(x, Wq, Wk, Wv, Wo, xb);

    gemm_mfma<1><<<1536, 256, 0, stream>>>(xb, Wqb, Wkb, Wvb, bq, bk, bv,
                                           Qb, Kb, Vb, nullptr);

    attn_mfma<<<1024, 256, 0, stream>>>(Qb, Kb, Vb, Ab);

    gemm_mfma<0><<<512, 256, 0, stream>>>(Ab, Wob, nullptr, nullptr, bo, nullptr, nullptr,
                                          nullptr, nullptr, nullptr, (float*)d_out);
}

// Round 5
// 279.971 us; speedup vs baseline: 35.6597x; 1.0410x over previous
//
#include <hip/hip_runtime.h>
#include <math.h>

// Problem constants (B,S,D,H) = (4,2048,1024,16), HD=64
#define BATCH 4
#define SEQ   2048
#define DMODEL 1024
#define NHEAD 16
#define HDIM  64
#define MROWS (BATCH*SEQ)   // 8192

typedef unsigned short u16;
typedef unsigned int   u32;

using bf16x8 = __attribute__((ext_vector_type(8))) short;
using f32x4  = __attribute__((ext_vector_type(4))) float;
using f32x16 = __attribute__((ext_vector_type(16))) float;

__device__ __forceinline__ u16 f2bf(float f) {
    u32 u = __float_as_uint(f);
    u += 0x7fffu + ((u >> 16) & 1u);
    return (u16)(u >> 16);
}
__device__ __forceinline__ u32 pack2bf(float a, float b) {
    u32 ua = __float_as_uint(a); ua += 0x7fffu + ((ua >> 16) & 1u);
    u32 ub = __float_as_uint(b); ub += 0x7fffu + ((ub >> 16) & 1u);
    return (ua >> 16) | (ub & 0xffff0000u);
}

// async global->LDS, 16 B per lane; LDS dest = wave-uniform base + lane*16
#define GLOBAL_LOAD_LDS16(gp, lp)                                              \
    __builtin_amdgcn_global_load_lds(                                          \
        (const __attribute__((address_space(1))) void*)(gp),                   \
        (__attribute__((address_space(3))) void*)(lp), 16, 0, 0)

// ---------------------------------------------------------------------------
// Convert x (8.4M) + Wq/Wk/Wv/Wo (1M each) fp32 -> bf16 into contiguous dst.
// ---------------------------------------------------------------------------
__global__ __launch_bounds__(256) void convert_inputs(
    const float* __restrict__ x,  const float* __restrict__ wq,
    const float* __restrict__ wk, const float* __restrict__ wv,
    const float* __restrict__ wo, u16* __restrict__ dst)
{
    long long i4 = ((long long)blockIdx.x * 256 + threadIdx.x) * 4;
    const float* src; long long off;
    if (i4 < 8388608LL) { src = x; off = i4; }
    else {
        long long j = i4 - 8388608LL;
        int seg = (int)(j >> 20);
        off = j & 1048575LL;
        src = (seg == 0) ? wq : (seg == 1) ? wk : (seg == 2) ? wv : wo;
    }
    float4 v = *(const float4*)(src + off);
    u32 lo = (u32)f2bf(v.x) | ((u32)f2bf(v.y) << 16);
    u32 hi = (u32)f2bf(v.z) | ((u32)f2bf(v.w) << 16);
    *(uint2*)(dst + i4) = make_uint2(lo, hi);
}

// ---------------------------------------------------------------------------
// bf16 MFMA GEMM: C[M,N] = A[M,K] @ W[N,K]^T + bias.  128x128 tile, BK=32.
// Staging via global_load_lds (16B/lane). LDS rows = 32 shorts (64 B);
// XOR swizzle phys_chunk = logical ^ ((row>>1)&3): with 64-B rows the bank
// group is 4*(row&1)+phys, so keying on (row>>1) spreads a 16-lane b128
// fragment read over all 8 bank groups (2 lanes each = conflict-free).
// Block mapping is XCD-aware (xcd = bx&7 round-robin): each XCD owns 8
// bm-tiles (2 MB of A, L2-resident) and streams W one 256 KB tile at a time.
// QKV=1: seg 0/1/2 = Q/K/V; epilogue RoPE(+0.125) / RoPE / plain bf16.
// QKV=0: fp32 output + bias (final projection).
// ---------------------------------------------------------------------------
template<int QKV>
__global__ __launch_bounds__(256) void gemm_mfma(
    const u16* __restrict__ A,
    const u16* __restrict__ Wq_, const u16* __restrict__ Wk_, const u16* __restrict__ Wv_,
    const float* __restrict__ bq_, const float* __restrict__ bk_, const float* __restrict__ bv_,
    u16* __restrict__ Cq_, u16* __restrict__ Ck_, u16* __restrict__ Cv_,
    float* __restrict__ Cf)
{
    __shared__ u16 As[128 * 32];
    __shared__ u16 Ws[128 * 32];

    const int t    = threadIdx.x;
    const int lane = t & 63;
    const int w    = t >> 6;
    const int quad = lane >> 4;
    const int l15  = lane & 15;

    // XCD-aware decode: xcd = bx&7; inner order bm-fastest, then n, then seg.
    const int bx  = blockIdx.x;
    const int xcd = bx & 7;
    const int i_  = bx >> 3;
    const int bml = i_ & 7;
    const int n_  = (QKV ? ((i_ >> 3) & 7) : (i_ >> 3));
    const int seg = (QKV ? (i_ >> 6) : 0);

    const u16*   W    = (seg == 0) ? Wq_ : (seg == 1) ? Wk_ : Wv_;
    const float* bias = (seg == 0) ? bq_ : (seg == 1) ? bk_ : bv_;
    u16*         Cb   = (seg == 0) ? Cq_ : (seg == 1) ? Ck_ : Cv_;

    const int bm   = (xcd * 8 + bml) * 128;
    const int bn   = n_ * 128;
    const int wrow = (w & 1) * 64;
    const int wcol = (w >> 1) * 64;

    // staging map: lane L -> row L>>2, phys chunk L&3, logical = phys ^ key,
    // key = ((row)>>1)&3 = (L>>3)&3
    const int srl = lane >> 2;
    const int sc  = (lane & 3) ^ ((lane >> 3) & 3);

    f32x4 acc[4][4] = {};

    for (int k0 = 0; k0 < DMODEL; k0 += 32) {
        __syncthreads();
        #pragma unroll
        for (int i = 0; i < 2; i++) {
            int row = 32 * w + 16 * i + srl;
            GLOBAL_LOAD_LDS16(A + (size_t)(bm + row) * DMODEL + k0 + sc * 8,
                              &As[(32 * w + 16 * i) * 32]);
            GLOBAL_LOAD_LDS16(W + (size_t)(bn + row) * DMODEL + k0 + sc * 8,
                              &Ws[(32 * w + 16 * i) * 32]);
        }
        __syncthreads();

        bf16x8 af[4], bfr[4];
        const int pc = quad ^ ((l15 >> 1) & 3);
        #pragma unroll
        for (int i = 0; i < 4; i++)
            af[i] = *(const bf16x8*)&As[(wrow + 16 * i + l15) * 32 + pc * 8];
        #pragma unroll
        for (int j = 0; j < 4; j++)
            bfr[j] = *(const bf16x8*)&Ws[(wcol + 16 * j + l15) * 32 + pc * 8];
        #pragma unroll
        for (int i = 0; i < 4; i++)
            #pragma unroll
            for (int j = 0; j < 4; j++)
                acc[i][j] = __builtin_amdgcn_mfma_f32_16x16x32_bf16(af[i], bfr[j], acc[i][j], 0, 0, 0);
    }

    // ---- epilogue
    float bv[4];
    #pragma unroll
    for (int j = 0; j < 4; j++) bv[j] = bias[bn + wcol + 16 * j + l15];

    if constexpr (QKV == 0) {
        #pragma unroll
        for (int i = 0; i < 4; i++)
            #pragma unroll
            for (int r = 0; r < 4; r++) {
                int mg = bm + wrow + 16 * i + quad * 4 + r;
                #pragma unroll
                for (int j = 0; j < 4; j++)
                    Cf[(size_t)mg * DMODEL + bn + wcol + 16 * j + l15] = acc[i][j][r] + bv[j];
            }
    } else {
        if (seg == 2) {
            #pragma unroll
            for (int i = 0; i < 4; i++)
                #pragma unroll
                for (int r = 0; r < 4; r++) {
                    int mg = bm + wrow + 16 * i + quad * 4 + r;
                    #pragma unroll
                    for (int j = 0; j < 4; j++)
                        Cb[(size_t)mg * DMODEL + bn + wcol + 16 * j + l15] = f2bf(acc[i][j][r] + bv[j]);
                }
        } else {
            // RoPE: wave's 64-col span = one head; pair (d, d+32) = j-tiles (j, j+2)
            const float qscale = (seg == 0) ? 0.125f : 1.0f;
            float inv[2];
            #pragma unroll
            for (int j = 0; j < 2; j++) {
                int d = 16 * j + l15;                              // 0..31
                inv[j] = exp2f(-(float)d * 0.4152410118609203f);   // 10000^(-d/32)
            }
            #pragma unroll
            for (int i = 0; i < 4; i++)
                #pragma unroll
                for (int r = 0; r < 4; r++) {
                    int mg = bm + wrow + 16 * i + quad * 4 + r;
                    int s  = mg & (SEQ - 1);
                    #pragma unroll
                    for (int j = 0; j < 2; j++) {
                        float f = (float)s * inv[j];
                        float sn, cs;
                        __sincosf(f, &sn, &cs);
                        float a1 = acc[i][j][r]     + bv[j];
                        float a2 = acc[i][j + 2][r] + bv[j + 2];
                        float o1 = (a1 * cs - a2 * sn) * qscale;
                        float o2 = (a2 * cs + a1 * sn) * qscale;
                        Cb[(size_t)mg * DMODEL + bn + wcol + 16 * j       + l15] = f2bf(o1);
                        Cb[(size_t)mg * DMODEL + bn + wcol + 16 * (j + 2) + l15] = f2bf(o2);
                    }
                }
        }
    }
}

// ---------------------------------------------------------------------------
// MFMA flash attention v2: 32x32x16 MFMA, 128 q-rows/block, max-free softmax.
// Wave w owns q rows [32w,32w+32). S^T = K*Q^T per 64-kr tile; exp; P via LDS
// (wave-private rows, no barrier); O += P@V with V staged transposed.
// All LDS tiles: 64-short rows, XOR swizzle phys_chunk = logical ^ (row&7).
// ---------------------------------------------------------------------------
__global__ __launch_bounds__(256) void attn_mfma(
    const u16* __restrict__ Q, const u16* __restrict__ K,
    const u16* __restrict__ V, u16* __restrict__ O)
{
    __shared__ u16 Qs[128 * 64];
    __shared__ u16 Ks[64 * 64];
    __shared__ u16 Vt[64 * 64];
    __shared__ u16 Ps[128 * 64];
    __shared__ float lS[128];

    const int t    = threadIdx.x;
    const int lane = t & 63;
    const int w    = t >> 6;
    const int l31  = lane & 31;
    const int hl   = lane >> 5;         // 0/1
    const int bid  = blockIdx.x;
    const int bh   = bid & 63;
    const int qt   = 15 - (bid >> 6);   // heavy q-tiles first
    const int h    = bh & (NHEAD - 1);
    const int b    = bh >> 4;
    const int q0   = qt * 128;

    const size_t gbase = ((size_t)b * SEQ) * DMODEL + h * HDIM;

    // ---- stage Q tile (128 rows) via global_load_lds, swizzled
    {
        int rl = lane >> 3, cp = lane & 7;
        int c  = cp ^ rl;                       // logical chunk
        #pragma unroll
        for (int i = 0; i < 4; i++) {
            int row = 32 * w + 8 * i + rl;
            GLOBAL_LOAD_LDS16(Q + gbase + (size_t)(q0 + row) * DMODEL + c * 8,
                              &Qs[(32 * w + 8 * i) * 64]);
        }
    }
    __syncthreads();

    // ---- hoist Q B-fragments (loop-invariant): B[k][n=q], k = hl*8+j+16s
    bf16x8 qf[4];
    {
        int row = 32 * w + l31;
        #pragma unroll
        for (int s = 0; s < 4; s++) {
            int c = (hl + 2 * s) ^ (row & 7);
            qf[s] = *(const bf16x8*)&Qs[row * 64 + c * 8];
        }
    }

    float lsum = 0.0f;
    f32x16 oacc[2] = {};

    const int ktn = 2 * qt + 2;
    for (int kt = 0; kt < ktn; kt++) {
        const int k0 = kt * 64;
        __syncthreads();   // protect Ks/Vt from previous iteration's readers

        // ---- stage K (64 rows) via global_load_lds, swizzled
        {
            int rl = lane >> 3, cp = lane & 7;
            int c  = cp ^ rl;
            #pragma unroll
            for (int i = 0; i < 2; i++) {
                int row = 16 * w + 8 * i + rl;
                GLOBAL_LOAD_LDS16(K + gbase + (size_t)(k0 + row) * DMODEL + c * 8,
                                  &Ks[(16 * w + 8 * i) * 64]);
            }
        }
        // ---- stage V transposed: Vt[d][j] = V[k0+j][d], swizzled pair-packed
        {
            int j0 = (t & 31) * 2, d0 = (t >> 5) * 8;
            uint4 va = *(const uint4*)(V + gbase + (size_t)(k0 + j0)     * DMODEL + d0);
            uint4 vb = *(const uint4*)(V + gbase + (size_t)(k0 + j0 + 1) * DMODEL + d0);
            const u16* pa = (const u16*)&va;
            const u16* pb = (const u16*)&vb;
            int jd = t & 31, pos = jd & 3, ch = jd >> 2;
            #pragma unroll
            for (int e = 0; e < 8; e++) {
                int row = d0 + e;
                int pcch = ch ^ (row & 7);
                *(u32*)&Vt[row * 64 + pcch * 8 + pos * 2] = (u32)pa[e] | ((u32)pb[e] << 16);
            }
        }
        __syncthreads();

        const bool act = (k0 <= q0 + 32 * w + 31);
        if (act) {
            const int qrow = 32 * w + l31;           // local q row
            const int qg   = q0 + qrow;              // global q row
            #pragma unroll
            for (int krh = 0; krh < 2; krh++) {
                const bool qact = (k0 + 32 * krh <= q0 + 32 * w + 31);
                if (!qact) {
                    // fully masked quadrant: P = 0
                    #pragma unroll
                    for (int g = 0; g < 4; g++)
                        #pragma unroll
                        for (int pp = 0; pp < 2; pp++) {
                            int kr = 32 * krh + 8 * g + 4 * hl + 2 * pp;
                            int jd = kr >> 1;
                            int pcc = (jd >> 2) ^ (qrow & 7);
                            *(u32*)&Ps[qrow * 64 + pcc * 8 + (jd & 3) * 2] = 0u;
                        }
                    continue;
                }
                // ---- S^T quadrant: D[m=kr][n=q]
                f32x16 s = {};
                #pragma unroll
                for (int stp = 0; stp < 4; stp++) {
                    int row = 32 * krh + l31;
                    int c   = (hl + 2 * stp) ^ (l31 & 7);
                    bf16x8 ka = *(const bf16x8*)&Ks[row * 64 + c * 8];
                    s = __builtin_amdgcn_mfma_f32_32x32x16_bf16(ka, qf[stp], s, 0, 0, 0);
                }
                // causal mask on diagonal-crossing tiles
                if (k0 + 32 * krh + 31 > q0 + 32 * w) {
                    #pragma unroll
                    for (int r = 0; r < 16; r++) {
                        int krg = k0 + 32 * krh + (r & 3) + 8 * (r >> 2) + 4 * hl;
                        if (krg > qg) s[r] = -1e30f;
                    }
                }
                // ---- exp (max-free), accumulate l, pack P to LDS
                float pv[16];
                #pragma unroll
                for (int r = 0; r < 16; r++) { pv[r] = __expf(s[r]); lsum += pv[r]; }
                #pragma unroll
                for (int g = 0; g < 4; g++)
                    #pragma unroll
                    for (int pp = 0; pp < 2; pp++) {
                        int kr = 32 * krh + 8 * g + 4 * hl + 2 * pp;
                        int jd = kr >> 1;
                        int pcc = (jd >> 2) ^ (qrow & 7);
                        *(u32*)&Ps[qrow * 64 + pcc * 8 + (jd & 3) * 2] =
                            pack2bf(pv[4 * g + 2 * pp], pv[4 * g + 2 * pp + 1]);
                    }
            }

            // ---- O += P @ V   (A = P rows q [wave-private], B = Vt rows d)
            #pragma unroll
            for (int stp = 0; stp < 4; stp++) {
                int c = (hl + 2 * stp) ^ (l31 & 7);
                bf16x8 pf = *(const bf16x8*)&Ps[qrow * 64 + c * 8];
                #pragma unroll
                for (int dh = 0; dh < 2; dh++) {
                    bf16x8 vf = *(const bf16x8*)&Vt[(32 * dh + l31) * 64 + c * 8];
                    oacc[dh] = __builtin_amdgcn_mfma_f32_32x32x16_bf16(pf, vf, oacc[dh], 0, 0, 0);
                }
            }
        }
    }

    // ---- finalize l (cross-half reduce, through LDS to reindex q)
    lsum += __shfl_xor(lsum, 32, 64);
    if (lane < 32) lS[32 * w + lane] = lsum;
    __syncthreads();

    // ---- writeout: O / l   (C layout: col=l31=d-local, row=(r&3)+8*(r>>2)+4*hl)
    #pragma unroll
    for (int g = 0; g < 4; g++) {
        f32x4 lv = *(const f32x4*)&lS[32 * w + 8 * g + 4 * hl];
        #pragma unroll
        for (int rr = 0; rr < 4; rr++) {
            int qg = q0 + 32 * w + rr + 8 * g + 4 * hl;
            float inv = 1.0f / lv[rr];
            #pragma unroll
            for (int dh = 0; dh < 2; dh++) {
                float o = oacc[dh][4 * g + rr] * inv;
                O[gbase + (size_t)qg * DMODEL + 32 * dh + l31] = f2bf(o);
            }
        }
    }
}

// ---------------------------------------------------------------------------
extern "C" void kernel_launch(void* const* d_in, const int* in_sizes, int n_in,
                              void* d_out, int out_size, void* d_ws, size_t ws_size,
                              hipStream_t stream)
{
    const float* x  = (const float*)d_in[0];
    const float* Wq = (const float*)d_in[1];
    const float* bq = (const float*)d_in[2];
    const float* Wk = (const float*)d_in[3];
    const float* bk = (const float*)d_in[4];
    const float* Wv = (const float*)d_in[5];
    const float* bv = (const float*)d_in[6];
    const float* Wo = (const float*)d_in[7];
    const float* bo = (const float*)d_in[8];

    u16* wsp = (u16*)d_ws;
    u16* xb  = wsp;                    // 8388608
    u16* Wqb = wsp + 8388608;          // 1048576 each
    u16* Wkb = Wqb + 1048576;
    u16* Wvb = Wkb + 1048576;
    u16* Wob = Wvb + 1048576;
    u16* Qb  = Wob + 1048576;          // 8388608 each
    u16* Kb  = Qb + 8388608;
    u16* Vb  = Kb + 8388608;
    u16* Ab  = Vb + 8388608;

    convert_inputs<<<12288, 256, 0, stream>>>(x, Wq, Wk, Wv, Wo, xb);

    gemm_mfma<1><<<1536, 256, 0, stream>>>(xb, Wqb, Wkb, Wvb, bq, bk, bv,
                                           Qb, Kb, Vb, nullptr);

    attn_mfma<<<1024, 256, 0, stream>>>(Qb, Kb, Vb, Ab);

    gemm_mfma<0><<<512, 256, 0, stream>>>(Ab, Wob, nullptr, nullptr, bo, nullptr, nullptr,
                                          nullptr, nullptr, nullptr, (float*)d_out);
}